// Round 1
// baseline (300.447 us; speedup 1.0000x reference)
//
#include <hip/hip_runtime.h>
#include <stdint.h>

#define NTOK 4096
#define HDIM 1024
#define DDIM 2048
#define NEXP 8
#define NASS 8192   // NTOK * K (K=2)

typedef __attribute__((ext_vector_type(8))) short bf16x8;
typedef __attribute__((ext_vector_type(4))) float f32x4;

__device__ __forceinline__ unsigned short f2bf(float f) {
  unsigned int u = __float_as_uint(f);
  return (unsigned short)((u + 0x7fffu + ((u >> 16) & 1u)) >> 16);
}

// ---------------- x fp32 -> bf16 ----------------
__global__ __launch_bounds__(256) void k_cvt_x(const float* __restrict__ x,
                                               unsigned short* __restrict__ x16) {
  int i = blockIdx.x * 256 + threadIdx.x;
  float4 v = reinterpret_cast<const float4*>(x)[i];
  ushort4 o;
  o.x = f2bf(v.x); o.y = f2bf(v.y); o.z = f2bf(v.z); o.w = f2bf(v.w);
  reinterpret_cast<ushort4*>(x16)[i] = o;
}

// ---------------- [E][R][C] fp32 -> [E][C][R] bf16 (tiled transpose) ----------------
__global__ __launch_bounds__(256) void k_transpose(const float* __restrict__ in,
                                                   unsigned short* __restrict__ out,
                                                   int R, int C) {
  __shared__ float t[32][33];
  const size_t mbase = (size_t)blockIdx.z * R * C;
  int tid = threadIdx.x;
  int r = tid >> 3, c4 = (tid & 7) * 4;
  int gr = blockIdx.y * 32 + r;
  int gc = blockIdx.x * 32 + c4;
  float4 v = *reinterpret_cast<const float4*>(in + mbase + (size_t)gr * C + gc);
  t[r][c4 + 0] = v.x; t[r][c4 + 1] = v.y; t[r][c4 + 2] = v.z; t[r][c4 + 3] = v.w;
  __syncthreads();
  int orow = blockIdx.x * 32 + r;    // original col
  int oc4  = blockIdx.y * 32 + c4;   // original row
  ushort4 o;
  o.x = f2bf(t[c4 + 0][r]); o.y = f2bf(t[c4 + 1][r]);
  o.z = f2bf(t[c4 + 2][r]); o.w = f2bf(t[c4 + 3][r]);
  *reinterpret_cast<ushort4*>(out + mbase + (size_t)orow * R + oc4) = o;
}

// ---------------- routing ----------------
// Detect index dtype: if int64, every odd 32-bit word (high word) is 0.
__global__ void k_detect(const int* __restrict__ idx, int* __restrict__ flag) {
  int i = blockIdx.x * 256 + threadIdx.x;
  if (i < NTOK) {
    if (idx[2 * i + 1] != 0) atomicOr(flag, 1);  // flag=1 -> plain int32 array
  }
}

__device__ __forceinline__ int load_eidx(const int* idx, int i, int is32) {
  return is32 ? idx[i] : idx[2 * i];
}

__global__ void k_count(const int* __restrict__ idx, int* __restrict__ counts,
                        const int* __restrict__ flag) {
  int i = blockIdx.x * 256 + threadIdx.x;
  if (i < NASS) atomicAdd(&counts[load_eidx(idx, i, *flag)], 1);
}

__global__ void k_scan(const int* __restrict__ counts, int* __restrict__ offs) {
  int off = 0;
  for (int e = 0; e < NEXP; ++e) { offs[e] = off; off += counts[e]; }
}

__global__ void k_scatter(const int* __restrict__ idx, const float* __restrict__ ew,
                          const int* __restrict__ amask, const int* __restrict__ flag,
                          const int* __restrict__ offs, int* __restrict__ cursor,
                          int* __restrict__ toks, float* __restrict__ wl) {
  int i = blockIdx.x * 256 + threadIdx.x;
  if (i < NASS) {
    int n = i >> 1;
    int e = load_eidx(idx, i, *flag);
    int pos = atomicAdd(&cursor[e], 1);
    int slot = offs[e] + pos;
    toks[slot] = n;
    wl[slot] = ew[i] * (amask[n] ? 1.0f : 0.0f);
  }
}

// ---------------- grouped GEMM: hid = relu(X[gather] @ down) ----------------
// A: gathered x16 rows [cnt][1024]; B: dnT [e][2048][1024] ([n][k], k contig)
__global__ __launch_bounds__(256) void k_gemm_down(
    const unsigned short* __restrict__ x16, const unsigned short* __restrict__ bT,
    const int* __restrict__ counts, const int* __restrict__ offs,
    const int* __restrict__ toks, unsigned short* __restrict__ hid) {
  const int e = blockIdx.z;
  const int cnt = counts[e];
  const int mt = blockIdx.y;
  if (mt * 128 >= cnt) return;
  const int nt = blockIdx.x;
  const int base = offs[e];
  __shared__ alignas(16) char lA[128 * 64 * 2];
  __shared__ alignas(16) char lB[128 * 64 * 2];
  const int tid = threadIdx.x;
  const int lane = tid & 63;
  const int wrow = (tid >> 7) * 64;
  const int wcol = ((tid >> 6) & 1) * 64;

  const unsigned short* srcA[4];
  const unsigned short* srcB[4];
  int dstO[4];
#pragma unroll
  for (int it = 0; it < 4; ++it) {
    int g = it * 256 + tid;
    int row = g >> 3;
    int col = (g & 7) * 8;
    int sl = mt * 128 + row; if (sl >= cnt) sl = cnt - 1;
    srcA[it] = x16 + (size_t)toks[base + sl] * HDIM + col;
    srcB[it] = bT + (size_t)e * DDIM * HDIM + (size_t)(nt * 128 + row) * HDIM + col;
    dstO[it] = (row * 128 + col * 2) ^ ((row & 7) << 4);
  }

  f32x4 acc[4][4] = {};
  for (int kk = 0; kk < HDIM; kk += 64) {
#pragma unroll
    for (int it = 0; it < 4; ++it) {
      int4 va = *reinterpret_cast<const int4*>(srcA[it] + kk);
      int4 vb = *reinterpret_cast<const int4*>(srcB[it] + kk);
      *reinterpret_cast<int4*>(lA + dstO[it]) = va;
      *reinterpret_cast<int4*>(lB + dstO[it]) = vb;
    }
    __syncthreads();
#pragma unroll
    for (int ks = 0; ks < 2; ++ks) {
      bf16x8 fa[4], fb[4];
#pragma unroll
      for (int m = 0; m < 4; ++m) {
        int row = wrow + m * 16 + (lane & 15);
        int off = (row * 128 + ks * 64 + ((lane >> 4) * 16)) ^ ((row & 7) << 4);
        fa[m] = *reinterpret_cast<const bf16x8*>(lA + off);
      }
#pragma unroll
      for (int n = 0; n < 4; ++n) {
        int row = wcol + n * 16 + (lane & 15);
        int off = (row * 128 + ks * 64 + ((lane >> 4) * 16)) ^ ((row & 7) << 4);
        fb[n] = *reinterpret_cast<const bf16x8*>(lB + off);
      }
#pragma unroll
      for (int m = 0; m < 4; ++m)
#pragma unroll
        for (int n = 0; n < 4; ++n)
          acc[m][n] = __builtin_amdgcn_mfma_f32_16x16x32_bf16(fa[m], fb[n], acc[m][n], 0, 0, 0);
    }
    __syncthreads();
  }

#pragma unroll
  for (int m = 0; m < 4; ++m) {
    int r0 = mt * 128 + wrow + m * 16 + ((lane >> 4) * 4);
#pragma unroll
    for (int j = 0; j < 4; ++j) {
      int r = r0 + j;
      if (r < cnt) {
        unsigned short* dst = hid + (size_t)(base + r) * DDIM + nt * 128 + wcol + (lane & 15);
#pragma unroll
        for (int n = 0; n < 4; ++n) {
          float v = acc[m][n][j];
          dst[n * 16] = f2bf(v > 0.f ? v : 0.f);
        }
      }
    }
  }
}

// ---------------- grouped GEMM: out[tok] += w * (hid @ up) ----------------
// A: hid slots [cnt][2048] bf16; B: upT [e][1024][2048] ([n][k], k contig)
__global__ __launch_bounds__(256) void k_gemm_up(
    const unsigned short* __restrict__ hid, const unsigned short* __restrict__ bT,
    const int* __restrict__ counts, const int* __restrict__ offs,
    const int* __restrict__ toks, const float* __restrict__ wl,
    float* __restrict__ out) {
  const int e = blockIdx.z;
  const int cnt = counts[e];
  const int mt = blockIdx.y;
  if (mt * 128 >= cnt) return;
  const int nt = blockIdx.x;
  const int base = offs[e];
  __shared__ alignas(16) char lA[128 * 64 * 2];
  __shared__ alignas(16) char lB[128 * 64 * 2];
  const int tid = threadIdx.x;
  const int lane = tid & 63;
  const int wrow = (tid >> 7) * 64;
  const int wcol = ((tid >> 6) & 1) * 64;

  const unsigned short* srcA[4];
  const unsigned short* srcB[4];
  int dstO[4];
#pragma unroll
  for (int it = 0; it < 4; ++it) {
    int g = it * 256 + tid;
    int row = g >> 3;
    int col = (g & 7) * 8;
    int sl = mt * 128 + row; if (sl >= cnt) sl = cnt - 1;
    srcA[it] = hid + (size_t)(base + sl) * DDIM + col;
    srcB[it] = bT + (size_t)e * HDIM * DDIM + (size_t)(nt * 128 + row) * DDIM + col;
    dstO[it] = (row * 128 + col * 2) ^ ((row & 7) << 4);
  }

  f32x4 acc[4][4] = {};
  for (int kk = 0; kk < DDIM; kk += 64) {
#pragma unroll
    for (int it = 0; it < 4; ++it) {
      int4 va = *reinterpret_cast<const int4*>(srcA[it] + kk);
      int4 vb = *reinterpret_cast<const int4*>(srcB[it] + kk);
      *reinterpret_cast<int4*>(lA + dstO[it]) = va;
      *reinterpret_cast<int4*>(lB + dstO[it]) = vb;
    }
    __syncthreads();
#pragma unroll
    for (int ks = 0; ks < 2; ++ks) {
      bf16x8 fa[4], fb[4];
#pragma unroll
      for (int m = 0; m < 4; ++m) {
        int row = wrow + m * 16 + (lane & 15);
        int off = (row * 128 + ks * 64 + ((lane >> 4) * 16)) ^ ((row & 7) << 4);
        fa[m] = *reinterpret_cast<const bf16x8*>(lA + off);
      }
#pragma unroll
      for (int n = 0; n < 4; ++n) {
        int row = wcol + n * 16 + (lane & 15);
        int off = (row * 128 + ks * 64 + ((lane >> 4) * 16)) ^ ((row & 7) << 4);
        fb[n] = *reinterpret_cast<const bf16x8*>(lB + off);
      }
#pragma unroll
      for (int m = 0; m < 4; ++m)
#pragma unroll
        for (int n = 0; n < 4; ++n)
          acc[m][n] = __builtin_amdgcn_mfma_f32_16x16x32_bf16(fa[m], fb[n], acc[m][n], 0, 0, 0);
    }
    __syncthreads();
  }

#pragma unroll
  for (int m = 0; m < 4; ++m) {
    int r0 = mt * 128 + wrow + m * 16 + ((lane >> 4) * 4);
#pragma unroll
    for (int j = 0; j < 4; ++j) {
      int r = r0 + j;
      if (r < cnt) {
        int slot = base + r;
        int tok = toks[slot];
        float w = wl[slot];
        float* dst = out + (size_t)tok * HDIM + nt * 128 + wcol + (lane & 15);
#pragma unroll
        for (int n = 0; n < 4; ++n) atomicAdd(dst + n * 16, w * acc[m][n][j]);
      }
    }
  }
}

extern "C" void kernel_launch(void* const* d_in, const int* in_sizes, int n_in,
                              void* d_out, int out_size, void* d_ws, size_t ws_size,
                              hipStream_t stream) {
  const float* x    = (const float*)d_in[0];
  const int* amask  = (const int*)d_in[1];
  const float* ew   = (const float*)d_in[2];
  const int* cidx   = (const int*)d_in[3];
  const float* dn   = (const float*)d_in[4];
  const float* up   = (const float*)d_in[5];
  float* out        = (float*)d_out;
  char* ws          = (char*)d_ws;

  const size_t X16_OFF = 0;
  const size_t DNT_OFF = X16_OFF + (size_t)NTOK * HDIM * 2;
  const size_t UPT_OFF = DNT_OFF + (size_t)NEXP * HDIM * DDIM * 2;
  const size_t HID_OFF = UPT_OFF + (size_t)NEXP * HDIM * DDIM * 2;
  const size_t LST_OFF = HID_OFF + (size_t)NASS * DDIM * 2;

  unsigned short* x16 = (unsigned short*)(ws + X16_OFF);
  unsigned short* dnT = (unsigned short*)(ws + DNT_OFF);
  unsigned short* upT = (unsigned short*)(ws + UPT_OFF);
  unsigned short* hid = (unsigned short*)(ws + HID_OFF);
  int* counts = (int*)(ws + LST_OFF);
  int* cursor = counts + 8;
  int* offs   = counts + 16;
  int* flag   = counts + 24;
  int* toks   = counts + 32;          // byte offset +128
  float* wl   = (float*)(toks + NASS);

  hipMemsetAsync(ws + LST_OFF, 0, 128, stream);
  k_cvt_x<<<NTOK * HDIM / 1024, 256, 0, stream>>>(x, x16);
  k_transpose<<<dim3(DDIM / 32, HDIM / 32, NEXP), 256, 0, stream>>>(dn, dnT, HDIM, DDIM);
  k_transpose<<<dim3(HDIM / 32, DDIM / 32, NEXP), 256, 0, stream>>>(up, upT, DDIM, HDIM);
  k_detect<<<16, 256, 0, stream>>>(cidx, flag);
  k_count<<<32, 256, 0, stream>>>(cidx, counts, flag);
  k_scan<<<1, 1, 0, stream>>>(counts, offs);
  k_scatter<<<32, 256, 0, stream>>>(cidx, ew, amask, flag, offs, cursor, toks, wl);
  hipMemcpyAsync(out, x, (size_t)NTOK * HDIM * 4, hipMemcpyDeviceToDevice, stream);
  k_gemm_down<<<dim3(DDIM / 128, 32, NEXP), 256, 0, stream>>>(x16, dnT, counts, offs, toks, hid);
  k_gemm_up<<<dim3(HDIM / 128, 32, NEXP), 256, 0, stream>>>(hid, upT, counts, offs, toks, wl, out);
}

// Round 2
// 187.287 us; speedup vs baseline: 1.6042x; 1.6042x over previous
//
#include <hip/hip_runtime.h>
#include <stdint.h>

#define NTOK 4096
#define HDIM 1024
#define DDIM 2048
#define NEXP 8
#define NASS 8192   // NTOK * K (K=2)

typedef __attribute__((ext_vector_type(8))) short bf16x8;
typedef __attribute__((ext_vector_type(4))) float f32x4;

typedef __attribute__((address_space(1))) const unsigned int gu32;
typedef __attribute__((address_space(3))) unsigned int lu32;

__device__ __forceinline__ void async16(void* lds, const void* g) {
  // global -> LDS direct copy, 16B per lane. LDS dest = wave base + lane*16 (linear).
  __builtin_amdgcn_global_load_lds((gu32*)(uintptr_t)g, (lu32*)(uintptr_t)lds, 16, 0, 0);
}

__device__ __forceinline__ unsigned short f2bf(float f) {
  unsigned int u = __float_as_uint(f);
  return (unsigned short)((u + 0x7fffu + ((u >> 16) & 1u)) >> 16);
}
__device__ __forceinline__ float bf2f(unsigned short u) {
  return __uint_as_float(((unsigned int)u) << 16);
}

// ---------------- x fp32 -> bf16 ----------------
__global__ __launch_bounds__(256) void k_cvt_x(const float* __restrict__ x,
                                               unsigned short* __restrict__ x16) {
  int i = blockIdx.x * 256 + threadIdx.x;
  float4 v = reinterpret_cast<const float4*>(x)[i];
  ushort4 o;
  o.x = f2bf(v.x); o.y = f2bf(v.y); o.z = f2bf(v.z); o.w = f2bf(v.w);
  reinterpret_cast<ushort4*>(x16)[i] = o;
}

// ---------------- [E][R][C] fp32 -> [E][C][R] bf16 (tiled transpose) ----------------
__global__ __launch_bounds__(256) void k_transpose(const float* __restrict__ in,
                                                   unsigned short* __restrict__ out,
                                                   int R, int C) {
  __shared__ float t[32][33];
  const size_t mbase = (size_t)blockIdx.z * R * C;
  int tid = threadIdx.x;
  int r = tid >> 3, c4 = (tid & 7) * 4;
  int gr = blockIdx.y * 32 + r;
  int gc = blockIdx.x * 32 + c4;
  float4 v = *reinterpret_cast<const float4*>(in + mbase + (size_t)gr * C + gc);
  t[r][c4 + 0] = v.x; t[r][c4 + 1] = v.y; t[r][c4 + 2] = v.z; t[r][c4 + 3] = v.w;
  __syncthreads();
  int orow = blockIdx.x * 32 + r;    // original col
  int oc4  = blockIdx.y * 32 + c4;   // original row
  ushort4 o;
  o.x = f2bf(t[c4 + 0][r]); o.y = f2bf(t[c4 + 1][r]);
  o.z = f2bf(t[c4 + 2][r]); o.w = f2bf(t[c4 + 3][r]);
  *reinterpret_cast<ushort4*>(out + mbase + (size_t)orow * R + oc4) = o;
}

// ---------------- routing: detect+count+scan+scatter in ONE block ----------------
__global__ __launch_bounds__(1024) void k_route(
    const int* __restrict__ idx, const float* __restrict__ ew,
    const int* __restrict__ amask,
    int* __restrict__ counts_g, int* __restrict__ offs_g,
    int* __restrict__ toks, float* __restrict__ wl, int* __restrict__ slotmap) {
  __shared__ int cnt[NEXP], cur[NEXP], flag;
  const int t = threadIdx.x;
  if (t < NEXP) cnt[t] = 0;
  if (t == 0) flag = 0;
  __syncthreads();
  // dtype detect: if int64, all high (odd) words are 0
  int lf = 0;
#pragma unroll
  for (int j = 0; j < 4; ++j) {
    int i = t + j * 1024;
    if (idx[2 * i + 1] != 0) lf = 1;
  }
  if (lf) atomicOr(&flag, 1);
  __syncthreads();
  const int is32 = flag;
  int e[8];
#pragma unroll
  for (int j = 0; j < 8; ++j) {
    int i = t + j * 1024;
    int ei = is32 ? idx[i] : idx[2 * i];
    e[j] = ei;
    atomicAdd(&cnt[ei], 1);
  }
  __syncthreads();
  if (t == 0) {
    int off = 0;
    for (int k = 0; k < NEXP; ++k) {
      cur[k] = off; offs_g[k] = off; counts_g[k] = cnt[k]; off += cnt[k];
    }
  }
  __syncthreads();
#pragma unroll
  for (int j = 0; j < 8; ++j) {
    int i = t + j * 1024;
    int n = i >> 1;
    int slot = atomicAdd(&cur[e[j]], 1);
    toks[slot] = n;
    wl[slot] = ew[i] * (amask[n] ? 1.0f : 0.0f);
    slotmap[i] = slot;
  }
}

// ---------------- grouped GEMM1: hid = relu(X[gather] @ down), m97 structure ----------------
// A: gathered x16 rows [cnt][1024]; B: dnT [e][2048][1024] (k contig). BK=64.
__global__ __launch_bounds__(256) void k_gemm_down(
    const unsigned short* __restrict__ x16, const unsigned short* __restrict__ bT,
    const int* __restrict__ counts, const int* __restrict__ offs,
    const int* __restrict__ toks, unsigned short* __restrict__ hid) {
  const int e = blockIdx.z;
  const int cnt = counts[e];
  const int mt = blockIdx.y;
  if (mt * 128 >= cnt) return;
  const int nt = blockIdx.x;
  const int base = offs[e];
  __shared__ alignas(16) char lds[32768];
  char* lA = lds;
  char* lB = lds + 16384;
  const int tid = threadIdx.x;
  const int lane = tid & 63;
  const int wave = tid >> 6;
  const int wrow = (tid >> 7) * 64;
  const int wcol = ((tid >> 6) & 1) * 64;

  // staging: rows of 64 bf16 (128B). LDS linear; global source pre-swizzled so that
  // LDS[row][c] = G[row][c ^ ((row&7)<<4)]  (rule #21: swizzle source + read, dest linear)
  const char* gA[4]; const char* gB[4]; char* sA[4]; char* sB[4];
  {
    const int swcol = ((lane & 7) << 4) ^ ((lane >> 3) << 4);
#pragma unroll
    for (int it = 0; it < 4; ++it) {
      int row = wave * 32 + it * 8 + (lane >> 3);
      int sl = mt * 128 + row; if (sl >= cnt) sl = cnt - 1;
      gA[it] = (const char*)(x16 + (size_t)toks[base + sl] * HDIM) + swcol;
      gB[it] = (const char*)(bT + (size_t)e * DDIM * HDIM + (size_t)(nt * 128 + row) * HDIM) + swcol;
      sA[it] = lA + wave * 4096 + it * 1024 + lane * 16;
      sB[it] = lB + wave * 4096 + it * 1024 + lane * 16;
    }
  }
  // fragment read offsets: row = (sub)tile row, swz = (lane&7)<<4 for all frags
  const int swz = (lane & 7) << 4;
  const int lo = ((lane >> 4) << 4);
  int rowA[4], rowB[4];
#pragma unroll
  for (int m = 0; m < 4; ++m) {
    rowA[m] = (wrow + m * 16 + (lane & 15)) * 128;
    rowB[m] = (wcol + m * 16 + (lane & 15)) * 128;
  }

  f32x4 acc[4][4] = {};
  for (int kk = 0; kk < HDIM; kk += 64) {
#pragma unroll
    for (int it = 0; it < 4; ++it) {
      async16(sA[it], gA[it] + kk * 2);
      async16(sB[it], gB[it] + kk * 2);
    }
    __syncthreads();   // compiler drains vmcnt before barrier
#pragma unroll
    for (int ks = 0; ks < 2; ++ks) {
      const int cx = ((ks << 6) | lo) ^ swz;
      bf16x8 fa[4], fb[4];
#pragma unroll
      for (int m = 0; m < 4; ++m) fa[m] = *reinterpret_cast<const bf16x8*>(lA + rowA[m] + cx);
#pragma unroll
      for (int n = 0; n < 4; ++n) fb[n] = *reinterpret_cast<const bf16x8*>(lB + rowB[n] + cx);
#pragma unroll
      for (int m = 0; m < 4; ++m)
#pragma unroll
        for (int n = 0; n < 4; ++n)
          acc[m][n] = __builtin_amdgcn_mfma_f32_16x16x32_bf16(fa[m], fb[n], acc[m][n], 0, 0, 0);
    }
    __syncthreads();
  }

#pragma unroll
  for (int m = 0; m < 4; ++m) {
    int r0 = mt * 128 + wrow + m * 16 + ((lane >> 4) * 4);
#pragma unroll
    for (int j = 0; j < 4; ++j) {
      int r = r0 + j;
      if (r < cnt) {
        unsigned short* dst = hid + (size_t)(base + r) * DDIM + nt * 128 + wcol + (lane & 15);
#pragma unroll
        for (int n = 0; n < 4; ++n) {
          float v = acc[m][n][j];
          dst[n * 16] = f2bf(v > 0.f ? v : 0.f);
        }
      }
    }
  }
}

// ---------------- grouped GEMM2 (K-split 2): yw[ksp][slot] = partial(hid @ up) ----------------
// A: hid slots [cnt][2048]; B: upT [e][1024][2048] (k contig). Partials stored bf16.
__global__ __launch_bounds__(256) void k_gemm_up(
    const unsigned short* __restrict__ hid, const unsigned short* __restrict__ bT,
    const int* __restrict__ counts, const int* __restrict__ offs,
    unsigned short* __restrict__ yw) {
  const int e = blockIdx.z;
  const int cnt = counts[e];
  const int mt = blockIdx.y;
  if (mt * 128 >= cnt) return;
  const int ksp = blockIdx.x >> 3;
  const int nt = blockIdx.x & 7;
  const int base = offs[e];
  __shared__ alignas(16) char lds[32768];
  char* lA = lds;
  char* lB = lds + 16384;
  const int tid = threadIdx.x;
  const int lane = tid & 63;
  const int wave = tid >> 6;
  const int wrow = (tid >> 7) * 64;
  const int wcol = ((tid >> 6) & 1) * 64;

  const char* gA[4]; const char* gB[4]; char* sA[4]; char* sB[4];
  {
    const int swcol = ((lane & 7) << 4) ^ ((lane >> 3) << 4);
#pragma unroll
    for (int it = 0; it < 4; ++it) {
      int row = wave * 32 + it * 8 + (lane >> 3);
      int sl = mt * 128 + row; if (sl >= cnt) sl = cnt - 1;
      gA[it] = (const char*)(hid + (size_t)(base + sl) * DDIM + ksp * 1024) + swcol;
      gB[it] = (const char*)(bT + (size_t)e * HDIM * DDIM + (size_t)(nt * 128 + row) * DDIM + ksp * 1024) + swcol;
      sA[it] = lA + wave * 4096 + it * 1024 + lane * 16;
      sB[it] = lB + wave * 4096 + it * 1024 + lane * 16;
    }
  }
  const int swz = (lane & 7) << 4;
  const int lo = ((lane >> 4) << 4);
  int rowA[4], rowB[4];
#pragma unroll
  for (int m = 0; m < 4; ++m) {
    rowA[m] = (wrow + m * 16 + (lane & 15)) * 128;
    rowB[m] = (wcol + m * 16 + (lane & 15)) * 128;
  }

  f32x4 acc[4][4] = {};
  for (int kk = 0; kk < 1024; kk += 64) {
#pragma unroll
    for (int it = 0; it < 4; ++it) {
      async16(sA[it], gA[it] + kk * 2);
      async16(sB[it], gB[it] + kk * 2);
    }
    __syncthreads();
#pragma unroll
    for (int ks = 0; ks < 2; ++ks) {
      const int cx = ((ks << 6) | lo) ^ swz;
      bf16x8 fa[4], fb[4];
#pragma unroll
      for (int m = 0; m < 4; ++m) fa[m] = *reinterpret_cast<const bf16x8*>(lA + rowA[m] + cx);
#pragma unroll
      for (int n = 0; n < 4; ++n) fb[n] = *reinterpret_cast<const bf16x8*>(lB + rowB[n] + cx);
#pragma unroll
      for (int m = 0; m < 4; ++m)
#pragma unroll
        for (int n = 0; n < 4; ++n)
          acc[m][n] = __builtin_amdgcn_mfma_f32_16x16x32_bf16(fa[m], fb[n], acc[m][n], 0, 0, 0);
    }
    __syncthreads();
  }

#pragma unroll
  for (int m = 0; m < 4; ++m) {
    int r0 = mt * 128 + wrow + m * 16 + ((lane >> 4) * 4);
#pragma unroll
    for (int j = 0; j < 4; ++j) {
      int r = r0 + j;
      if (r < cnt) {
        unsigned short* dst = yw + ((size_t)ksp * NASS + base + r) * HDIM
                              + nt * 128 + wcol + (lane & 15);
#pragma unroll
        for (int n = 0; n < 4; ++n) dst[n * 16] = f2bf(acc[m][n][j]);
      }
    }
  }
}

// ---------------- combine: out = x + w0*(p00+p01) + w1*(p10+p11) ----------------
__global__ __launch_bounds__(256) void k_combine(
    const float* __restrict__ x, const unsigned short* __restrict__ yw,
    const int* __restrict__ slotmap, const float* __restrict__ wl,
    float* __restrict__ out) {
  const int n = blockIdx.x;
  const int t = threadIdx.x;
  const int s0 = slotmap[2 * n], s1 = slotmap[2 * n + 1];
  const float w0 = wl[s0], w1 = wl[s1];
  float4 xv = reinterpret_cast<const float4*>(x + (size_t)n * HDIM)[t];
  ushort4 a0 = reinterpret_cast<const ushort4*>(yw + (size_t)s0 * HDIM)[t];
  ushort4 a1 = reinterpret_cast<const ushort4*>(yw + ((size_t)NASS + s0) * HDIM)[t];
  ushort4 b0 = reinterpret_cast<const ushort4*>(yw + (size_t)s1 * HDIM)[t];
  ushort4 b1 = reinterpret_cast<const ushort4*>(yw + ((size_t)NASS + s1) * HDIM)[t];
  float4 r;
  r.x = xv.x + w0 * (bf2f(a0.x) + bf2f(a1.x)) + w1 * (bf2f(b0.x) + bf2f(b1.x));
  r.y = xv.y + w0 * (bf2f(a0.y) + bf2f(a1.y)) + w1 * (bf2f(b0.y) + bf2f(b1.y));
  r.z = xv.z + w0 * (bf2f(a0.z) + bf2f(a1.z)) + w1 * (bf2f(b0.z) + bf2f(b1.z));
  r.w = xv.w + w0 * (bf2f(a0.w) + bf2f(a1.w)) + w1 * (bf2f(b0.w) + bf2f(b1.w));
  reinterpret_cast<float4*>(out + (size_t)n * HDIM)[t] = r;
}

extern "C" void kernel_launch(void* const* d_in, const int* in_sizes, int n_in,
                              void* d_out, int out_size, void* d_ws, size_t ws_size,
                              hipStream_t stream) {
  const float* x    = (const float*)d_in[0];
  const int* amask  = (const int*)d_in[1];
  const float* ew   = (const float*)d_in[2];
  const int* cidx   = (const int*)d_in[3];
  const float* dn   = (const float*)d_in[4];
  const float* up   = (const float*)d_in[5];
  float* out        = (float*)d_out;
  char* ws          = (char*)d_ws;

  const size_t X16_OFF = 0;
  const size_t DNT_OFF = X16_OFF + (size_t)NTOK * HDIM * 2;             // 8.4MB
  const size_t UPT_OFF = DNT_OFF + (size_t)NEXP * HDIM * DDIM * 2;      // +33.5MB
  const size_t HID_OFF = UPT_OFF + (size_t)NEXP * HDIM * DDIM * 2;      // +33.5MB
  const size_t MET_OFF = HID_OFF + (size_t)NASS * DDIM * 2;             // +33.5MB

  unsigned short* x16 = (unsigned short*)(ws + X16_OFF);
  unsigned short* dnT = (unsigned short*)(ws + DNT_OFF);
  unsigned short* upT = (unsigned short*)(ws + UPT_OFF);
  unsigned short* hid = (unsigned short*)(ws + HID_OFF);
  // yw ([2][NASS][HDIM] bf16, 33.5MB) aliases dnT: dnT is dead once k_gemm_down completes
  unsigned short* yw  = (unsigned short*)(ws + DNT_OFF);
  int* counts  = (int*)(ws + MET_OFF);
  int* offs    = counts + 8;
  int* toks    = counts + 32;
  float* wl    = (float*)(toks + NASS);
  int* slotmap = (int*)(wl + NASS);

  k_cvt_x<<<NTOK * HDIM / 1024, 256, 0, stream>>>(x, x16);
  k_transpose<<<dim3(DDIM / 32, HDIM / 32, NEXP), 256, 0, stream>>>(dn, dnT, HDIM, DDIM);
  k_transpose<<<dim3(HDIM / 32, DDIM / 32, NEXP), 256, 0, stream>>>(up, upT, DDIM, HDIM);
  k_route<<<1, 1024, 0, stream>>>(cidx, ew, amask, counts, offs, toks, wl, slotmap);
  k_gemm_down<<<dim3(DDIM / 128, 32, NEXP), 256, 0, stream>>>(x16, dnT, counts, offs, toks, hid);
  k_gemm_up<<<dim3(16, 32, NEXP), 256, 0, stream>>>(hid, upT, counts, offs, yw);
  k_combine<<<NTOK, 256, 0, stream>>>(x, yw, slotmap, wl, out);
}